// Round 3
// baseline (70.382 us; speedup 1.0000x reference)
//
#include <hip/hip_runtime.h>
#include <hip/hip_bf16.h>

#define BB 8
#define NN 2048
#define FF 128

typedef __bf16 bf16x8 __attribute__((ext_vector_type(8)));
typedef float f32x4 __attribute__((ext_vector_type(4)));

// ---------------------------------------------------------------------------
// Kernel A: Wh = h @ W (bf16 MFMA, fp32 accum), then
//   - src = Wh·a1, dst = Wh·a2 (fp32)
//   - Wh converted to bf16 and written to global in MFMA B-fragment order:
//     fragB[((b*64+J)*8 + ft)*64 + lane][e] = Wh[J*32 + (lane>>4)*8 + e][ft*16 + (lane&15)]
// ---------------------------------------------------------------------------
__global__ __launch_bounds__(256) void wh_kernel(
    const float* __restrict__ h, const float* __restrict__ W,
    const float* __restrict__ a, __bf16* __restrict__ fragB,
    float* __restrict__ srcg, float* __restrict__ dstg)
{
    __shared__ __bf16 s_wh[32][132];   // +4 pad: conflict-free frag transpose
    __shared__ float  s_s[2][32];
    __shared__ float  s_d[2][32];

    const int bid = blockIdx.x;
    const int b   = bid >> 6;
    const int J   = bid & 63;
    const int r0  = J * 32;
    const int t   = threadIdx.x;
    const int w   = t >> 6;
    const int l   = t & 63;
    const int itile = w & 1;
    const int fh    = w >> 1;
    const int g     = l >> 4;
    const int c16   = l & 15;

    const float* hrow = h + (size_t)(b * NN + r0 + itile * 16 + c16) * FF;

    f32x4 acc[4] = {};

#pragma unroll
    for (int kt = 0; kt < 4; ++kt) {
        const int k0 = kt * 32 + g * 8;
        f32x4 h0 = *(const f32x4*)(hrow + k0);
        f32x4 h1 = *(const f32x4*)(hrow + k0 + 4);
        bf16x8 af;
        af[0]=(__bf16)h0[0]; af[1]=(__bf16)h0[1]; af[2]=(__bf16)h0[2]; af[3]=(__bf16)h0[3];
        af[4]=(__bf16)h1[0]; af[5]=(__bf16)h1[1]; af[6]=(__bf16)h1[2]; af[7]=(__bf16)h1[3];
#pragma unroll
        for (int ft = 0; ft < 4; ++ft) {
            const int c = (fh * 4 + ft) * 16 + c16;
            bf16x8 bf;
#pragma unroll
            for (int e = 0; e < 8; ++e) bf[e] = (__bf16)W[(k0 + e) * FF + c];
            acc[ft] = __builtin_amdgcn_mfma_f32_16x16x32_bf16(af, bf, acc[ft], 0, 0, 0);
        }
    }

    // C layout: col = lane&15, row = (lane>>4)*4 + reg
    float a1v[4], a2v[4];
#pragma unroll
    for (int ft = 0; ft < 4; ++ft) {
        const int c = (fh * 4 + ft) * 16 + c16;
        a1v[ft] = a[c];
        a2v[ft] = a[FF + c];
    }
#pragma unroll
    for (int r = 0; r < 4; ++r) {
        float s = 0.f, d2 = 0.f;
#pragma unroll
        for (int ft = 0; ft < 4; ++ft) {
            s  += acc[ft][r] * a1v[ft];
            d2 += acc[ft][r] * a2v[ft];
        }
#pragma unroll
        for (int m = 1; m <= 8; m <<= 1) {
            s  += __shfl_xor(s,  m);
            d2 += __shfl_xor(d2, m);
        }
        if (c16 == 0) {
            s_s[fh][itile * 16 + g * 4 + r] = s;
            s_d[fh][itile * 16 + g * 4 + r] = d2;
        }
    }

    // Wh -> LDS (bf16)
#pragma unroll
    for (int ft = 0; ft < 4; ++ft)
#pragma unroll
        for (int r = 0; r < 4; ++r)
            s_wh[itile * 16 + g * 4 + r][(fh * 4 + ft) * 16 + c16] = (__bf16)acc[ft][r];

    __syncthreads();

    // re-read in B-fragment order and store (16B per lane, coalesced)
#pragma unroll
    for (int e2 = 0; e2 < 2; ++e2) {
        const int ent  = t + e2 * 256;        // 0..511 = ft*64 + lane
        const int ftE  = ent >> 6;
        const int lE   = ent & 63;
        const int rowE = (lE >> 4) * 8;
        const int colE = ftE * 16 + (lE & 15);
        bf16x8 v;
#pragma unroll
        for (int ee = 0; ee < 8; ++ee) v[ee] = s_wh[rowE + ee][colE];
        *(bf16x8*)(fragB + ((size_t)((b * 64 + J) * 8 + ftE) * 64 + lE) * 8) = v;
    }

    if (t < 32) {
        srcg[b * NN + r0 + t] = s_s[0][t] + s_s[1][t];
        dstg[b * NN + r0 + t] = s_d[0][t] + s_d[1][t];
    }
}

// ---------------------------------------------------------------------------
// Kernel B v3: in-block j-split for occupancy.
// 512-thread blocks (8 waves) = {2 itile x 2 fh x 2 jhalf}; each wave sweeps
// 32 of the 64 K-steps; partials combined in LDS at the tail (no extra HBM).
// Inner loop stays barrier-free: frags direct from global (L2-resident),
// adj+frag double-buffered one K-step ahead in registers.
// ---------------------------------------------------------------------------

#define LOADK(kt_, A0_, A1_, f0_, f1_, f2_, f3_)                              \
    {                                                                         \
        const int j0_ = (jbase + (kt_)) * 32 + g * 8;                         \
        A0_ = *(const int4*)(adjrow + j0_);                                   \
        A1_ = *(const int4*)(adjrow + j0_ + 4);                               \
        const bf16x8* fp_ = fw + (size_t)(jbase + (kt_)) * 512;               \
        f0_ = fp_[0];                                                         \
        f1_ = fp_[64];                                                        \
        f2_ = fp_[128];                                                       \
        f3_ = fp_[192];                                                       \
    }

#define COMPUTEK(kt_, A0_, A1_, f0_, f1_, f2_, f3_)                           \
    {                                                                         \
        const int j0_ = (jbase + (kt_)) * 32 + g * 8;                         \
        const f32x4 d0_ = *(const f32x4*)(s_dst + j0_);                       \
        const f32x4 d1_ = *(const f32x4*)(s_dst + j0_ + 4);                   \
        const int   am_[8] = {A0_.x, A0_.y, A0_.z, A0_.w,                     \
                              A1_.x, A1_.y, A1_.z, A1_.w};                    \
        const float dv_[8] = {d0_[0], d0_[1], d0_[2], d0_[3],                 \
                              d1_[0], d1_[1], d1_[2], d1_[3]};                \
        bf16x8 af_;                                                           \
        _Pragma("unroll")                                                     \
        for (int e = 0; e < 8; ++e) {                                         \
            float x = sv + dv_[e];                                            \
            x = fmaxf(x, 0.2f * x);                                           \
            float p = __expf(x);                                              \
            p = (am_[e] > 0) ? p : 0.f;                                       \
            psum += p;                                                        \
            af_[e] = (__bf16)p;                                               \
        }                                                                     \
        acc[0] = __builtin_amdgcn_mfma_f32_16x16x32_bf16(af_, f0_, acc[0], 0, 0, 0); \
        acc[1] = __builtin_amdgcn_mfma_f32_16x16x32_bf16(af_, f1_, acc[1], 0, 0, 0); \
        acc[2] = __builtin_amdgcn_mfma_f32_16x16x32_bf16(af_, f2_, acc[2], 0, 0, 0); \
        acc[3] = __builtin_amdgcn_mfma_f32_16x16x32_bf16(af_, f3_, acc[3], 0, 0, 0); \
    }

__global__ __launch_bounds__(512, 4) void attn_kernel(
    const int* __restrict__ adj, const __bf16* __restrict__ fragB,
    const float* __restrict__ srcg, const float* __restrict__ dstg,
    float* __restrict__ out)
{
    __shared__ float s_dst[NN];             // 8 KB
    __shared__ float s_comb[4][64][16];     // 16 KB partial-acc handoff
    __shared__ float s_psum[4][64];         // 1 KB

    const int bid0 = blockIdx.x;
    const int bid  = (bid0 & 7) * 64 + (bid0 >> 3);   // bijective, 512 % 8 == 0
    const int b    = bid >> 6;
    const int I0   = (bid & 63) * 32;
    const int t    = threadIdx.x;
    const int w    = t >> 6;                // 0..7
    const int l    = t & 63;
    const int itile = w & 1;
    const int fh    = (w >> 1) & 1;
    const int jhalf = w >> 2;
    const int widx  = w & 3;
    const int g     = l >> 4;
    const int c16   = l & 15;
    const int lrow  = itile * 16 + c16;
    const int jbase = jhalf * 32;           // K-step base (32 j per step)

    // stage dst[b][*] into LDS (2048 floats), once
    {
        const f32x4* gs = (const f32x4*)(dstg + (size_t)b * NN);
        ((f32x4*)s_dst)[t] = gs[t];
    }
    __syncthreads();

    const float sv = srcg[b * NN + I0 + lrow];
    const int* adjrow = adj + (size_t)(b * NN + I0 + lrow) * NN;
    // wave's frag base: entry ((b*64+kt)*8 + fh*4+ft)*64 + l, 16 B each
    const bf16x8* fw = (const bf16x8*)fragB + (size_t)b * 32768 + (fh * 4) * 64 + l;

    f32x4 acc[4] = {};
    float psum = 0.f;

    int4  Aa0, Aa1, Ab0, Ab1;
    bf16x8 Fa0, Fa1, Fa2, Fa3, Fb0, Fb1, Fb2, Fb3;

    LOADK(0, Aa0, Aa1, Fa0, Fa1, Fa2, Fa3);

    for (int kt = 0; kt < 32; kt += 2) {
        LOADK(kt + 1, Ab0, Ab1, Fb0, Fb1, Fb2, Fb3);
        COMPUTEK(kt, Aa0, Aa1, Fa0, Fa1, Fa2, Fa3);
        const int ktn = (kt + 2 < 32) ? kt + 2 : 0;   // tail: dummy reload of 0
        LOADK(ktn, Aa0, Aa1, Fa0, Fa1, Fa2, Fa3);
        COMPUTEK(kt + 1, Ab0, Ab1, Fb0, Fb1, Fb2, Fb3);
    }

    // ---- combine the two j-halves in LDS ----
    if (jhalf == 1) {
#pragma unroll
        for (int ft = 0; ft < 4; ++ft)
#pragma unroll
            for (int r = 0; r < 4; ++r)
                s_comb[widx][l][ft * 4 + r] = acc[ft][r];
        s_psum[widx][l] = psum;
    }
    __syncthreads();
    if (jhalf == 0) {
        psum += s_psum[widx][l];
#pragma unroll
        for (int ft = 0; ft < 4; ++ft)
#pragma unroll
            for (int r = 0; r < 4; ++r)
                acc[ft][r] += s_comb[widx][l][ft * 4 + r];

        // denom: reduce over the 4 k-groups (lanes l, l^16, l^32, l^48)
        psum += __shfl_xor(psum, 16);
        psum += __shfl_xor(psum, 32);

#pragma unroll
        for (int r = 0; r < 4; ++r) {
            const float dinv = 1.f / __shfl(psum, g * 4 + r);  // lane g*4+r has c16 == g*4+r
            const int row = I0 + itile * 16 + g * 4 + r;
#pragma unroll
            for (int ft = 0; ft < 4; ++ft) {
                const int col = (fh * 4 + ft) * 16 + c16;
                out[(size_t)(b * NN + row) * FF + col] = acc[ft][r] * dinv;
            }
        }
    }
}

// ---------------------------------------------------------------------------
extern "C" void kernel_launch(void* const* d_in, const int* in_sizes, int n_in,
                              void* d_out, int out_size, void* d_ws, size_t ws_size,
                              hipStream_t stream)
{
    const float* h   = (const float*)d_in[0];
    const int*   adj = (const int*)d_in[1];
    const float* W   = (const float*)d_in[2];
    const float* a   = (const float*)d_in[3];
    float* out = (float*)d_out;

    char* ws = (char*)d_ws;
    __bf16* fragB = (__bf16*)ws;                              // 4 MiB
    float*  srcg  = (float*)(ws + (4 << 20));                 // 64 KiB
    float*  dstg  = (float*)(ws + (4 << 20) + (64 << 10));    // 64 KiB

    wh_kernel<<<512, 256, 0, stream>>>(h, W, a, fragB, srcg, dstg);
    attn_kernel<<<512, 512, 0, stream>>>(adj, fragB, srcg, dstg, out);
}

// Round 4
// 44.166 us; speedup vs baseline: 1.5936x; 1.5936x over previous
//
#include <hip/hip_runtime.h>
#include <hip/hip_bf16.h>

#define BB 8
#define NN 2048
#define FF 128

typedef __bf16 bf16x8 __attribute__((ext_vector_type(8)));
typedef float f32x4 __attribute__((ext_vector_type(4)));

__device__ __forceinline__ void gload_lds16(const void* g, void* l) {
    __builtin_amdgcn_global_load_lds(
        (const __attribute__((address_space(1))) unsigned int*)g,
        (__attribute__((address_space(3))) unsigned int*)l, 16, 0, 0);
}

// ---------------------------------------------------------------------------
// Kernel A: Wh = h @ W (bf16 MFMA), src/dst rowvecs, fragB in MFMA B-frag
// order: fragB[((b*64+J)*8 + ft)*64 + lane][e] =
//        Wh[J*32 + (lane>>4)*8 + e][ft*16 + (lane&15)]
// h staged coalesced through LDS (was 16B/lane @ 512B stride from global).
// ---------------------------------------------------------------------------
__global__ __launch_bounds__(256) void wh_kernel(
    const float* __restrict__ h, const float* __restrict__ W,
    const float* __restrict__ a, __bf16* __restrict__ fragB,
    float* __restrict__ srcg, float* __restrict__ dstg)
{
    __shared__ float  s_h[32][132];    // +4 pad
    __shared__ __bf16 s_wh[32][132];
    __shared__ float  s_s[2][32];
    __shared__ float  s_d[2][32];

    const int bid = blockIdx.x;
    const int b   = bid >> 6;
    const int J   = bid & 63;
    const int r0  = J * 32;
    const int t   = threadIdx.x;
    const int w   = t >> 6;
    const int l   = t & 63;
    const int itile = w & 1;
    const int fh    = w >> 1;
    const int g     = l >> 4;
    const int c16   = l & 15;

    // cooperative coalesced load of the 32x128 h tile
#pragma unroll
    for (int i = 0; i < 4; ++i) {
        const int idx = t + i * 256;       // 0..1023 f32x4 units
        const int r   = idx >> 5;
        const int c4  = idx & 31;
        *(f32x4*)&s_h[r][c4 * 4] =
            *(const f32x4*)(h + (size_t)(b * NN + r0 + r) * FF + c4 * 4);
    }
    __syncthreads();

    const float* hrow = &s_h[itile * 16 + c16][0];

    f32x4 acc[4] = {};

#pragma unroll
    for (int kt = 0; kt < 4; ++kt) {
        const int k0 = kt * 32 + g * 8;
        f32x4 h0 = *(const f32x4*)(hrow + k0);
        f32x4 h1 = *(const f32x4*)(hrow + k0 + 4);
        bf16x8 af;
        af[0]=(__bf16)h0[0]; af[1]=(__bf16)h0[1]; af[2]=(__bf16)h0[2]; af[3]=(__bf16)h0[3];
        af[4]=(__bf16)h1[0]; af[5]=(__bf16)h1[1]; af[6]=(__bf16)h1[2]; af[7]=(__bf16)h1[3];
#pragma unroll
        for (int ft = 0; ft < 4; ++ft) {
            const int c = (fh * 4 + ft) * 16 + c16;
            bf16x8 bf;
#pragma unroll
            for (int e = 0; e < 8; ++e) bf[e] = (__bf16)W[(k0 + e) * FF + c];
            acc[ft] = __builtin_amdgcn_mfma_f32_16x16x32_bf16(af, bf, acc[ft], 0, 0, 0);
        }
    }

    float a1v[4], a2v[4];
#pragma unroll
    for (int ft = 0; ft < 4; ++ft) {
        const int c = (fh * 4 + ft) * 16 + c16;
        a1v[ft] = a[c];
        a2v[ft] = a[FF + c];
    }
#pragma unroll
    for (int r = 0; r < 4; ++r) {
        float s = 0.f, d2 = 0.f;
#pragma unroll
        for (int ft = 0; ft < 4; ++ft) {
            s  += acc[ft][r] * a1v[ft];
            d2 += acc[ft][r] * a2v[ft];
        }
#pragma unroll
        for (int m = 1; m <= 8; m <<= 1) {
            s  += __shfl_xor(s,  m);
            d2 += __shfl_xor(d2, m);
        }
        if (c16 == 0) {
            s_s[fh][itile * 16 + g * 4 + r] = s;
            s_d[fh][itile * 16 + g * 4 + r] = d2;
        }
    }

#pragma unroll
    for (int ft = 0; ft < 4; ++ft)
#pragma unroll
        for (int r = 0; r < 4; ++r)
            s_wh[itile * 16 + g * 4 + r][(fh * 4 + ft) * 16 + c16] = (__bf16)acc[ft][r];

    __syncthreads();

#pragma unroll
    for (int e2 = 0; e2 < 2; ++e2) {
        const int ent  = t + e2 * 256;
        const int ftE  = ent >> 6;
        const int lE   = ent & 63;
        const int rowE = (lE >> 4) * 8;
        const int colE = ftE * 16 + (lE & 15);
        bf16x8 v;
#pragma unroll
        for (int ee = 0; ee < 8; ++ee) v[ee] = s_wh[rowE + ee][colE];
        *(bf16x8*)(fragB + ((size_t)((b * 64 + J) * 8 + ftE) * 64 + lE) * 8) = v;
    }

    if (t < 32) {
        srcg[b * NN + r0 + t] = s_s[0][t] + s_s[1][t];
        dstg[b * NN + r0 + t] = s_d[0][t] + s_d[1][t];
    }
}

// ---------------------------------------------------------------------------
// Kernel B v4: counted-vmcnt global_load_lds pipeline (T3/T4 pattern).
// 4 waves = {itile in 0..1} x {jhalf in 0..1}; 32 block-steps of 64 j.
//   adj:  depth-4 LDS pipe, 8 KB/step, source-XOR-swizzled (conflict-free read)
//   frag: depth-2 LDS pipe, 16 KB/step (L2-resident panel)
// Per step/wave: 6 global_load_lds, 1 raw s_barrier, vmcnt(2) (never 0).
// No exp duplication (jhalf split); tail combine of j-half partials in LDS.
// ---------------------------------------------------------------------------
__global__ __launch_bounds__(256, 2) void attn_kernel(
    const int* __restrict__ adj, const __bf16* __restrict__ fragB,
    const float* __restrict__ srcg, const float* __restrict__ dstg,
    float* __restrict__ out)
{
    __shared__ char  s_pipe[65536];   // [0,32K): adj 4 slots x 8K ; [32K,64K): frag 2 slots x 16K
    __shared__ float s_dst[NN];       // 8 KB
    __shared__ float s_ps[2][64];

    const int bid0 = blockIdx.x;
    const int bid  = (bid0 & 7) * 64 + (bid0 >> 3);   // bijective XCD swizzle
    const int b    = bid >> 6;
    const int I0   = (bid & 63) * 32;
    const int t    = threadIdx.x;
    const int w    = t >> 6;          // wave: it = w>>1, h = w&1
    const int l    = t & 63;
    const int it   = w >> 1;
    const int h    = w & 1;
    const int g    = l >> 4;
    const int c16  = l & 15;

    // ---- stage dst (2048 f32) into LDS ----
    {
        const f32x4* gs = (const f32x4*)(dstg + (size_t)b * NN);
        ((f32x4*)s_dst)[t]       = gs[t];
        ((f32x4*)s_dst)[t + 256] = gs[t + 256];
    }

    // ---- per-lane staging source pointers ----
    // adj chunks (this wave's tile = (it,h), rowblocks rb=0,1), source XOR-
    // swizzled so linear LDS + swizzled read is conflict-free:
    //   lane L: row = I0+it*16+rb*8+(L>>3), 16B-unit = (L&7)^(L>>3)
    const char* adjB  = (const char*)adj;
    const size_t rA0  = (size_t)(b * NN + I0 + it * 16 + (l >> 3)) * (NN * 4)
                        + h * 128 + 16 * ((l & 7) ^ (l >> 3));
    const char* aSrc0 = adjB + rA0;
    const char* aSrc1 = adjB + rA0 + (size_t)8 * NN * 4;
    char* aDst0 = s_pipe + (w * 2 + 0) * 1024;
    char* aDst1 = s_pipe + (w * 2 + 1) * 1024;

    // frag chunks: fcIdx = w*4+i  ->  (h' = fcIdx>>3, fc = fcIdx&7)
    const char* fragBB = (const char*)fragB + (size_t)b * 524288;
    const char* fSrc0 = fragBB + ((w*4+0) >> 3) * 8192 + ((w*4+0) & 7) * 1024 + l * 16;
    const char* fSrc1 = fragBB + ((w*4+1) >> 3) * 8192 + ((w*4+1) & 7) * 1024 + l * 16;
    const char* fSrc2 = fragBB + ((w*4+2) >> 3) * 8192 + ((w*4+2) & 7) * 1024 + l * 16;
    const char* fSrc3 = fragBB + ((w*4+3) >> 3) * 8192 + ((w*4+3) & 7) * 1024 + l * 16;
    char* fDst0 = s_pipe + 32768 + (w*4+0) * 1024;
    char* fDst1 = s_pipe + 32768 + (w*4+1) * 1024;
    char* fDst2 = s_pipe + 32768 + (w*4+2) * 1024;
    char* fDst3 = s_pipe + 32768 + (w*4+3) * 1024;

#define STAGE_A(kA_, sl_) {                                                   \
        gload_lds16(aSrc0 + (size_t)(kA_) * 256, aDst0 + (sl_) * 8192);       \
        gload_lds16(aSrc1 + (size_t)(kA_) * 256, aDst1 + (sl_) * 8192); }
#define STAGE_F(kF_, sl_) {                                                   \
        gload_lds16(fSrc0 + (size_t)(kF_) * 16384, fDst0 + (sl_) * 16384);    \
        gload_lds16(fSrc1 + (size_t)(kF_) * 16384, fDst1 + (sl_) * 16384);    \
        gload_lds16(fSrc2 + (size_t)(kF_) * 16384, fDst2 + (sl_) * 16384);    \
        gload_lds16(fSrc3 + (size_t)(kF_) * 16384, fDst3 + (sl_) * 16384); }

    // prologue: A(0),A(1),F(0),A(2)  -> newest-2 = A(2), so vmcnt(2) retires F(0)
    STAGE_A(0, 0);
    STAGE_A(1, 1);
    STAGE_F(0, 0);
    STAGE_A(2, 2);

    const float sv = srcg[b * NN + I0 + it * 16 + c16];
    const int   sw = (c16 & 7) << 4;

    f32x4 acc[8] = {};
    float psum = 0.f;

    for (int kt = 0; kt < 32; ++kt) {
        // own stage(kt) instrs retired (F(kt) + everything older); keep 2
        // newest (A-stages) in flight across the barrier.
        asm volatile("s_waitcnt vmcnt(2) lgkmcnt(0)" ::: "memory");
        __builtin_amdgcn_s_barrier();
        asm volatile("" ::: "memory");

        // stage ahead (wrapped at the tail into never-again-read slots)
        const int kF = (kt + 1) & 31;
        const int kA = (kt + 3) & 31;
        STAGE_F(kF, (kt + 1) & 1);
        STAGE_A(kA, (kt + 3) & 3);

        // ---- compute step kt ----
        const char* atile = s_pipe + (kt & 3) * 8192 + w * 2048 + c16 * 128;
        const int4 A0 = *(const int4*)(atile + ((g * 32)      ^ sw));
        const int4 A1 = *(const int4*)(atile + ((g * 32 + 16) ^ sw));
        const int j0 = kt * 64 + h * 32 + g * 8;
        const f32x4 d0 = *(const f32x4*)(s_dst + j0);
        const f32x4 d1 = *(const f32x4*)(s_dst + j0 + 4);
        const int   am[8] = {A0.x, A0.y, A0.z, A0.w, A1.x, A1.y, A1.z, A1.w};
        const float dv[8] = {d0[0], d0[1], d0[2], d0[3], d1[0], d1[1], d1[2], d1[3]};

        bf16x8 af;
#pragma unroll
        for (int e = 0; e < 8; ++e) {
            float x = sv + dv[e];
            x = fmaxf(x, 0.2f * x);          // leaky_relu 0.2
            float p = __expf(x);             // bounded, no max-sub needed
            p = (am[e] > 0) ? p : 0.f;
            psum += p;
            af[e] = (__bf16)p;
        }

        const char* ftile = s_pipe + 32768 + (kt & 1) * 16384 + h * 8192 + l * 16;
#pragma unroll
        for (int ft = 0; ft < 8; ++ft) {
            const bf16x8 bf = *(const bf16x8*)(ftile + ft * 1024);
            acc[ft] = __builtin_amdgcn_mfma_f32_16x16x32_bf16(af, bf, acc[ft], 0, 0, 0);
        }
    }

    // per-wave row-sum over its j-half (replicated across g)
    psum += __shfl_xor(psum, 16);
    psum += __shfl_xor(psum, 32);

    // ---- combine j-halves (reuse pipe LDS) ----
    __syncthreads();
    float* s_comb = (float*)s_pipe;          // [2][64][33]
    if (h == 1) {
        float* cb = s_comb + (it * 64 + l) * 33;
#pragma unroll
        for (int ft = 0; ft < 8; ++ft)
#pragma unroll
            for (int r = 0; r < 4; ++r) cb[ft * 4 + r] = acc[ft][r];
        s_ps[it][l] = psum;
    }
    __syncthreads();
    if (h == 0) {
        psum += s_ps[it][l];
        const float* cb = s_comb + (it * 64 + l) * 33;
#pragma unroll
        for (int ft = 0; ft < 8; ++ft)
#pragma unroll
            for (int r = 0; r < 4; ++r) acc[ft][r] += cb[ft * 4 + r];

#pragma unroll
        for (int r = 0; r < 4; ++r) {
            const float dinv = 1.f / __shfl(psum, g * 4 + r);
            const int row = I0 + it * 16 + g * 4 + r;
            float* orow = out + (size_t)(b * NN + row) * FF + c16;
#pragma unroll
            for (int ft = 0; ft < 8; ++ft) orow[ft * 16] = acc[ft][r] * dinv;
        }
    }
#undef STAGE_A
#undef STAGE_F
}

// ---------------------------------------------------------------------------
extern "C" void kernel_launch(void* const* d_in, const int* in_sizes, int n_in,
                              void* d_out, int out_size, void* d_ws, size_t ws_size,
                              hipStream_t stream)
{
    const float* h   = (const float*)d_in[0];
    const int*   adj = (const int*)d_in[1];
    const float* W   = (const float*)d_in[2];
    const float* a   = (const float*)d_in[3];
    float* out = (float*)d_out;

    char* ws = (char*)d_ws;
    __bf16* fragB = (__bf16*)ws;                              // 4 MiB
    float*  srcg  = (float*)(ws + (4 << 20));                 // 64 KiB
    float*  dstg  = (float*)(ws + (4 << 20) + (64 << 10));    // 64 KiB

    wh_kernel<<<512, 256, 0, stream>>>(h, W, a, fragB, srcg, dstg);
    attn_kernel<<<512, 256, 0, stream>>>(adj, fragB, srcg, dstg, out);
}